// Round 1
// baseline (42.555 us; speedup 1.0000x reference)
//
#include <hip/hip_runtime.h>

// Problem constants (from reference setup_inputs / module constants)
#define BB 16
#define HH 256
#define WW 256
#define CC 32
#define HO 256
#define WO 256

// One thread = one float4 (4 channels) of one output pixel.
// 8 threads per output pixel; 64-lane wave covers 8 pixels.
__global__ __launch_bounds__(256) void bilinear_kernel(
    const float* __restrict__ X,   // [B, H, W, C]
    const float* __restrict__ t,   // [B, 6]
    float* __restrict__ out)       // [B, HO, WO, C]
{
    int i = blockIdx.x * blockDim.x + threadIdx.x;
    int pix = i >> 3;           // output pixel index in [0, B*HO*WO)
    int c4  = (i & 7) << 2;     // channel offset: 0,4,...,28

    int b  = pix >> 16;         // / (HO*WO) = / 65536
    int p  = pix & 65535;
    int oy = p >> 8;            // / WO
    int ox = p & 255;           // % WO

    // linspace(-1,1,256): step 2/255, 'xy' meshgrid -> xc varies with ox, yc with oy
    float xc = ox * (2.0f / 255.0f) - 1.0f;
    float yc = oy * (2.0f / 255.0f) - 1.0f;

    const float* th = t + b * 6;
    float th0 = th[0], th1 = th[1], th2 = th[2];
    float th3 = th[3], th4 = th[4], th5 = th[5];

    float xs = th0 * xc + th1 * yc + th2;
    float ys = th3 * xc + th4 * yc + th5;

    // faithful to reference: x scaled by H, y by W (both 256 here)
    float x = 0.5f * (xs + 1.0f) * (float)HH;
    float y = 0.5f * (ys + 1.0f) * (float)WW;

    // astype(int32) truncates toward zero; C cast matches
    int x0 = (int)x;
    int x1 = x0 + 1;
    int y0 = (int)y;
    int y1 = y0 + 1;
    x0 = min(max(x0, 0), WW - 1);
    x1 = min(max(x1, 0), WW - 1);
    y0 = min(max(y0, 0), HH - 1);
    y1 = min(max(y1, 0), HH - 1);

    float x0f = (float)x0, x1f = (float)x1;
    float y0f = (float)y0, y1f = (float)y1;

    // weights from clipped corner coords, unclipped x/y (matches reference)
    float wa = (x1f - x) * (y1f - y);
    float wb = (x1f - x) * (y - y0f);
    float wc = (x - x0f) * (y1f - y);
    float wd = (x - x0f) * (y - y0f);

    const int rowb = b * HH * WW;   // base pixel index for this batch image
    const float4* pa = (const float4*)(X + (size_t)((rowb + y0 * WW + x0) * CC + c4));
    const float4* pb = (const float4*)(X + (size_t)((rowb + y1 * WW + x0) * CC + c4));
    const float4* pc = (const float4*)(X + (size_t)((rowb + y0 * WW + x1) * CC + c4));
    const float4* pd = (const float4*)(X + (size_t)((rowb + y1 * WW + x1) * CC + c4));

    float4 va = *pa;
    float4 vb = *pb;
    float4 vc = *pc;
    float4 vd = *pd;

    float4 r;
    r.x = wa * va.x + wb * vb.x + wc * vc.x + wd * vd.x;
    r.y = wa * va.y + wb * vb.y + wc * vc.y + wd * vd.y;
    r.z = wa * va.z + wb * vb.z + wc * vc.z + wd * vd.z;
    r.w = wa * va.w + wb * vb.w + wc * vc.w + wd * vd.w;

    *(float4*)(out + (size_t)pix * CC + c4) = r;
}

extern "C" void kernel_launch(void* const* d_in, const int* in_sizes, int n_in,
                              void* d_out, int out_size, void* d_ws, size_t ws_size,
                              hipStream_t stream) {
    const float* X = (const float*)d_in[0];
    const float* t = (const float*)d_in[1];
    float* out = (float*)d_out;

    // total threads = B*HO*WO*8 = 8,388,608 -> 32768 blocks of 256
    const int total = BB * HO * WO * 8;
    const int block = 256;
    const int grid = total / block;
    bilinear_kernel<<<grid, block, 0, stream>>>(X, t, out);
}